// Round 4
// baseline (220.046 us; speedup 1.0000x reference)
//
#include <hip/hip_runtime.h>
#include <hip/hip_bf16.h>
#include <stdint.h>
#include <type_traits>

#define BS 4
#define LEN 5440
#define ROWS (BS * LEN)     // 21760 = 340 * 64

typedef __bf16 bf16;
typedef __bf16 bf16x2 __attribute__((ext_vector_type(2)));
typedef __bf16 bf16x4 __attribute__((ext_vector_type(4)));
typedef __bf16 bf16x8 __attribute__((ext_vector_type(8)));
typedef float f32x4 __attribute__((ext_vector_type(4)));

// ---------------------------------------------------------------------------
// Weight prep (single dispatch): transpose+cast weights to bf16 BT[N][256],
// build concatenated [off|attn] bias. grid = 897 x 256.
// ---------------------------------------------------------------------------
__global__ __launch_bounds__(256) void prep_weights(
    const float* __restrict__ vproj_w, const float* __restrict__ off_w,
    const float* __restrict__ attn_w, const float* __restrict__ out_w,
    const float* __restrict__ off_b, const float* __restrict__ attn_b,
    bf16* __restrict__ bt_v, bf16* __restrict__ bt_oa, bf16* __restrict__ bt_out,
    float* __restrict__ bias_oa)
{
    const int n = blockIdx.x;
    const int k = threadIdx.x;
    if (n == 896) {
        bias_oa[k] = off_b[k];
        if (k < 128) bias_oa[256 + k] = attn_b[k];
        return;
    }
    const float* W; bf16* dst; int col, N;
    if (n < 256)      { W = vproj_w; N = 256; col = n;       dst = bt_v   + n * 256; }
    else if (n < 512) { W = off_w;   N = 256; col = n - 256; dst = bt_oa  + (n - 256) * 256; }
    else if (n < 640) { W = attn_w;  N = 128; col = n - 512; dst = bt_oa  + (n - 256) * 256; }
    else              { W = out_w;   N = 256; col = n - 640; dst = bt_out + (n - 640) * 256; }
    dst[k] = (bf16)W[k * N + col];
}

// ---------------------------------------------------------------------------
// GEMM body: C[M][256..384] tile = A[64 rows][K=256] @ BT^T[128 cols] + bias.
// Block 256 thr = 4 waves. Whole 128x256 B-stripe staged once in 64 KB LDS
// (16B-chunk XOR swizzle). Wave w: cols w*32..+31 (2 ntiles), all 64 rows
// (4 mtiles). Its 16 B-fragments are loaded ONCE into registers (64 VGPR),
// A streamed from global -> MFMA:ds_read = 4:1.
// ---------------------------------------------------------------------------
template <typename AT, typename OutT>
__device__ __forceinline__ void gemm_body(
    const AT* __restrict__ A, const bf16* __restrict__ BT,
    const float* __restrict__ bias, OutT* __restrict__ C,
    int N, int n0, int m0, int tid)
{
    __shared__ bf16 sB[128 * 256];   // 64 KB

    const int wave = tid >> 6;
    const int lane = tid & 63;
    const int l15  = lane & 15;
    const int quad = lane >> 4;
    const int sw   = l15 & 7;

    {
        const int4* src = (const int4*)(BT + (size_t)n0 * 256);
        int4* dst = (int4*)sB;
#pragma unroll
        for (int it = 0; it < 16; ++it) {
            int c = tid + it * 256;
            int n = c >> 5;
            int kc = c & 31;
            dst[(n << 5) | (kc ^ (n & 7))] = src[c];
        }
    }
    __syncthreads();

    // B fragments -> registers (2 ntiles x 8 ki)
    bf16x8 bfr[2][8];
#pragma unroll
    for (int nt = 0; nt < 2; ++nt) {
        const int nn = wave * 32 + nt * 16 + l15;
#pragma unroll
        for (int ki = 0; ki < 8; ++ki) {
            const int kc = (ki << 2) + quad;
            bfr[nt][ki] = *(const bf16x8*)(sB + (((nn << 5) | (kc ^ sw)) << 3));
        }
    }

    f32x4 acc[4][2] = {};

#pragma unroll
    for (int mt = 0; mt < 4; ++mt) {
        const int row = m0 + mt * 16 + l15;
        const AT* arow = A + (size_t)row * 256 + quad * 8;
        bf16x8 afr[8];
#pragma unroll
        for (int ki = 0; ki < 8; ++ki) {
            if constexpr (std::is_same_v<AT, float>) {
                float4 f0 = *(const float4*)(arow + ki * 32);
                float4 f1 = *(const float4*)(arow + ki * 32 + 4);
                afr[ki] = bf16x8{(bf16)f0.x, (bf16)f0.y, (bf16)f0.z, (bf16)f0.w,
                                 (bf16)f1.x, (bf16)f1.y, (bf16)f1.z, (bf16)f1.w};
            } else {
                afr[ki] = *(const bf16x8*)(arow + ki * 32);
            }
        }
#pragma unroll
        for (int ki = 0; ki < 8; ++ki) {
#pragma unroll
            for (int nt = 0; nt < 2; ++nt)
                acc[mt][nt] = __builtin_amdgcn_mfma_f32_16x16x32_bf16(
                    afr[ki], bfr[nt][ki], acc[mt][nt], 0, 0, 0);
        }
    }

#pragma unroll
    for (int mt = 0; mt < 4; ++mt) {
#pragma unroll
        for (int nt = 0; nt < 2; ++nt) {
            const int col = n0 + wave * 32 + nt * 16 + l15;
            const float bv = bias[col];
#pragma unroll
            for (int r = 0; r < 4; ++r) {
                const int rr = m0 + mt * 16 + (quad << 2) + r;
                float val = acc[mt][nt][r] + bv;
                if constexpr (std::is_same_v<OutT, float>)
                    C[(uint32_t)(rr * N + col)] = val;
                else
                    C[(uint32_t)(rr * N + col)] = (bf16)val;
            }
        }
    }
}

// Front GEMMs fused: bx<2 -> value@vproj (N=256) ; bx>=2 -> query@[off|attn] (N=384)
__global__ __launch_bounds__(256) void gemm_front(
    const float* __restrict__ value, const float* __restrict__ query,
    const bf16* __restrict__ bt_v, const bf16* __restrict__ bt_oa,
    const float* __restrict__ bias_v, const float* __restrict__ bias_oa,
    bf16* __restrict__ v_bf, bf16* __restrict__ oa_bf)
{
    const int bx = blockIdx.x;
    const int m0 = blockIdx.y * 64;
    if (bx < 2)
        gemm_body<float, bf16>(value, bt_v, bias_v, v_bf, 256, bx * 128, m0, threadIdx.x);
    else
        gemm_body<float, bf16>(query, bt_oa, bias_oa, oa_bf, 384, (bx - 2) * 128, m0, threadIdx.x);
}

__global__ __launch_bounds__(256) void gemm_back(
    const bf16* __restrict__ pre, const bf16* __restrict__ bt_out,
    const float* __restrict__ out_b, float* __restrict__ out)
{
    gemm_body<bf16, float>(pre, bt_out, out_b, out, 256, blockIdx.x * 128,
                           blockIdx.y * 64, threadIdx.x);
}

// ---------------------------------------------------------------------------
// Fused softmax + multi-scale bilinear sampling, two-phase, conflict-free LDS.
// Per-(q,h) row stride padded to 17 float4 -> head h hits banks 4h..4h+3.
// ---------------------------------------------------------------------------
__global__ __launch_bounds__(256) void msda_sample(
    const bf16* __restrict__ v,        // [BS][LEN][256]
    const float* __restrict__ ref_pts, // [BS][LEN][4][2]
    const bf16* __restrict__ oa,       // [BS][LEN][384]: off 0..255, attn 256..383
    bf16* __restrict__ pre)            // [BS][LEN][256]
{
    const int ib = blockIdx.x;
    const int b  = (ib & 7) >> 1;                 // batch per XCD-pair
    const int qg = ((ib >> 3) << 1) + (ib & 1);
    const int q0 = qg * 4;
    const int tid = threadIdx.x;

    __shared__ float  s_ref[32];
    __shared__ float  s_wn[512];
    __shared__ float4 s_tw[544];    // [32 (q,h)][16 pt] stride 17
    __shared__ int4   s_to[544];

    const uint32_t rowbase = (uint32_t)(b * LEN + q0);

    if (tid < 32) {
        s_ref[tid] = ref_pts[rowbase * 8 + tid];
        const int qi = tid >> 3, h = tid & 7;
        const bf16* ap = oa + (rowbase + qi) * 384 + 256 + h * 16;
        bf16x8 l0 = *(const bf16x8*)ap;
        bf16x8 l1 = *(const bf16x8*)(ap + 8);
        float lg[16];
#pragma unroll
        for (int i = 0; i < 8; ++i) { lg[i] = (float)l0[i]; lg[8 + i] = (float)l1[i]; }
        float m = -1e30f;
#pragma unroll
        for (int i = 0; i < 16; ++i) m = fmaxf(m, lg[i]);
        float s = 0.f;
#pragma unroll
        for (int i = 0; i < 16; ++i) { lg[i] = __expf(lg[i] - m); s += lg[i]; }
        const float inv = 1.f / s;
#pragma unroll
        for (int i = 0; i < 16; ++i) s_wn[qi * 128 + h * 16 + i] = lg[i] * inv;
    }
    __syncthreads();

    // Phase 1: 512 items (q,h,pt), 2 per thread
#pragma unroll
    for (int it = 0; it < 2; ++it) {
        const int item = tid + it * 256;
        const int g  = item >> 4;         // (qi*8 + h)
        const int qi = item >> 7;
        const int h  = (item >> 4) & 7;
        const int pt = item & 15;
        const int l  = pt >> 2;
        const int iw = 64 >> l;
        const int st = (l == 0) ? 0 : ((l == 1) ? 4096 : ((l == 2) ? 5120 : 5376));
        const float fiw = (float)iw;

        bf16x2 ob = *(const bf16x2*)(oa + (rowbase + qi) * 384 + (h * 16 + pt) * 2);
        const float x = s_ref[qi * 8 + l * 2 + 0] * fiw - 0.5f + (float)ob[0];
        const float y = s_ref[qi * 8 + l * 2 + 1] * fiw - 0.5f + (float)ob[1];
        const float x0f = floorf(x), y0f = floorf(y);
        const int x0 = (int)x0f, y0 = (int)y0f;
        const int x1 = x0 + 1, y1 = y0 + 1;
        const float fx = x - x0f, fy = y - y0f;
        const float wa = s_wn[qi * 128 + h * 16 + pt];
        const float w00 = (1.f - fx) * (1.f - fy) * wa;
        const float w10 = (1.f - fx) * fy * wa;
        const float w01 = fx * (1.f - fy) * wa;
        const float w11 = fx * fy * wa;
        const bool xi0 = (x0 >= 0) & (x0 < iw);
        const bool xi1 = (x1 >= 0) & (x1 < iw);
        const bool yi0 = (y0 >= 0) & (y0 < iw);
        const bool yi1 = (y1 >= 0) & (y1 < iw);
        const int xc0 = min(max(x0, 0), iw - 1), xc1 = min(max(x1, 0), iw - 1);
        const int yc0 = min(max(y0, 0), iw - 1), yc1 = min(max(y1, 0), iw - 1);
        const int hb = h * 64;
        s_tw[g * 17 + pt] = make_float4((xi0 & yi0) ? w00 : 0.f, (xi0 & yi1) ? w10 : 0.f,
                                        (xi1 & yi0) ? w01 : 0.f, (xi1 & yi1) ? w11 : 0.f);
        s_to[g * 17 + pt] = make_int4(((st + yc0 * iw + xc0) << 9) + hb,
                                      ((st + yc1 * iw + xc0) << 9) + hb,
                                      ((st + yc0 * iw + xc1) << 9) + hb,
                                      ((st + yc1 * iw + xc1) << 9) + hb);
    }
    __syncthreads();

    // Phase 2: branch-free gather-accumulate
    const int qi = tid >> 6;
    const int u  = tid & 63;
    const int h  = u >> 3;
    const int c8 = u & 7;
    const char* vbc = (const char*)(v + (uint32_t)b * (LEN * 256));
    const uint32_t lb = (uint32_t)(c8 * 8);
    const int base = (qi * 8 + h) * 17;

    float a0 = 0.f, a1 = 0.f, a2 = 0.f, a3 = 0.f;
#pragma unroll
    for (int pt = 0; pt < 16; ++pt) {
        const float4 w4 = s_tw[base + pt];
        const int4   o4 = s_to[base + pt];
#define TAP(OFF, W) { \
        uint2 d = *(const uint2*)(vbc + ((uint32_t)(OFF) + lb)); \
        a0 = fmaf(__uint_as_float(d.x << 16),          (W), a0); \
        a1 = fmaf(__uint_as_float(d.x & 0xffff0000u),  (W), a1); \
        a2 = fmaf(__uint_as_float(d.y << 16),          (W), a2); \
        a3 = fmaf(__uint_as_float(d.y & 0xffff0000u),  (W), a3); }
        TAP(o4.x, w4.x)
        TAP(o4.y, w4.y)
        TAP(o4.z, w4.z)
        TAP(o4.w, w4.w)
#undef TAP
    }

    bf16x4 o = {(bf16)a0, (bf16)a1, (bf16)a2, (bf16)a3};
    *(bf16x4*)(pre + (rowbase + qi) * 256 + h * 32 + c8 * 4) = o;
}

// ---------------------------------------------------------------------------
// Launch: 4 dispatches
// ---------------------------------------------------------------------------
extern "C" void kernel_launch(void* const* d_in, const int* in_sizes, int n_in,
                              void* d_out, int out_size, void* d_ws, size_t ws_size,
                              hipStream_t stream) {
    const float* query   = (const float*)d_in[0];
    const float* ref_pts = (const float*)d_in[1];
    const float* value   = (const float*)d_in[2];
    const float* vproj_w = (const float*)d_in[5];
    const float* vproj_b = (const float*)d_in[6];
    const float* off_w   = (const float*)d_in[7];
    const float* off_b   = (const float*)d_in[8];
    const float* attn_w  = (const float*)d_in[9];
    const float* attn_b  = (const float*)d_in[10];
    const float* out_w   = (const float*)d_in[11];
    const float* out_b   = (const float*)d_in[12];
    float* out = (float*)d_out;

    bf16* ws = (bf16*)d_ws;
    bf16* v_bf    = ws;                                // ROWS*256
    bf16* oa_bf   = v_bf   + (size_t)ROWS * 256;       // ROWS*384
    bf16* pre_bf  = oa_bf  + (size_t)ROWS * 384;       // ROWS*256
    bf16* bt_v    = pre_bf + (size_t)ROWS * 256;       // 256*256
    bf16* bt_oa   = bt_v   + 256 * 256;                // 384*256
    bf16* bt_out  = bt_oa  + 384 * 256;                // 256*256
    float* bias_oa = (float*)(bt_out + 256 * 256);     // 384 f32

    dim3 blk(256);

    prep_weights<<<dim3(897), blk, 0, stream>>>(vproj_w, off_w, attn_w, out_w,
                                                off_b, attn_b, bt_v, bt_oa, bt_out, bias_oa);

    gemm_front<<<dim3(5, 340), blk, 0, stream>>>(value, query, bt_v, bt_oa,
                                                 vproj_b, bias_oa, v_bf, oa_bf);

    msda_sample<<<dim3(5440), blk, 0, stream>>>(v_bf, ref_pts, oa_bf, pre_bf);

    gemm_back<<<dim3(2, 340), blk, 0, stream>>>(pre_bf, bt_out, out_b, out);
}